// Round 7
// baseline (133.282 us; speedup 1.0000x reference)
//
#include <hip/hip_runtime.h>
#include <hip/hip_bf16.h>

// B=8, T1=128, T2=256, C=256, H=8, hd=32, E=32, A1=16, NTYPE=3. fp32 in HBM.
// Round 7: vaux eliminated algebraically (va@Wp = ax1@(Wv_a1@Wp) = ax1@Weff,
// Weff precomputed 16x256); softmax scale folded into q GEMM epilogue;
// prep merged to one dispatch. GEMM/attn cores unchanged (absmax 9.77e-4).
#define NC 256
#define HD 32

typedef __attribute__((ext_vector_type(8))) short short8;
typedef __attribute__((ext_vector_type(4))) short short4v;
typedef __attribute__((ext_vector_type(4))) float f32x4;

#define QSC (0.17677669529663687f * 1.4426950408889634f)  // 1/sqrt(32)*log2(e)

__device__ __forceinline__ unsigned short f2bf(float f) {
    union { float f; unsigned u; } v; v.f = f;
    unsigned r = v.u + 0x7fffu + ((v.u >> 16) & 1u);   // RNE
    return (unsigned short)(r >> 16);
}
__device__ __forceinline__ short8 cvt8(float4 a, float4 b) {
    short8 s;
    s[0] = (short)f2bf(a.x); s[1] = (short)f2bf(a.y);
    s[2] = (short)f2bf(a.z); s[3] = (short)f2bf(a.w);
    s[4] = (short)f2bf(b.x); s[5] = (short)f2bf(b.y);
    s[6] = (short)f2bf(b.z); s[7] = (short)f2bf(b.w);
    return s;
}

// ---------------------------------------------------------------------------
// prep (merged): activations + masks + weight transposes, all coalesced.
//  0..63    x1b        64..351 A2=[x2|ax2|0]   352..355 ax1p
//  356..547 mask bits  548..643 WqT   644..859 WkT/WvT   860..955 WpT
// ---------------------------------------------------------------------------
__global__ __launch_bounds__(256) void prep(
    const float* __restrict__ x1, const float* __restrict__ x2,
    const float* __restrict__ ax1, const float* __restrict__ ax2,
    const int* __restrict__ masks,
    const float* __restrict__ Wq, const float* __restrict__ Wk,
    const float* __restrict__ Wv, const float* __restrict__ Wp,
    short* __restrict__ x1b, short* __restrict__ A2, short* __restrict__ ax1p,
    unsigned int* __restrict__ mb,
    short* __restrict__ WqT, short* __restrict__ WkT, short* __restrict__ WvT,
    short* __restrict__ WpT)
{
    const int bx = blockIdx.x, tid = threadIdx.x;
    const short8 zero8 = {0, 0, 0, 0, 0, 0, 0, 0};

    if (bx < 64) {                                  // x1 -> x1b
        const size_t base = ((size_t)bx * 256 + tid) * 16;
        const float* p = x1 + base;
        float4 a = *(const float4*)p,       b = *(const float4*)(p + 4);
        float4 c = *(const float4*)(p + 8), d = *(const float4*)(p + 12);
        *(short8*)&x1b[base]     = cvt8(a, b);
        *(short8*)&x1b[base + 8] = cvt8(c, d);
    } else if (bx < 352) {                          // A2: 2048 rows x 36 col8
        const int g = (bx - 64) * 256 + tid;
        const int row = g / 36, c8 = g - row * 36;
        short8 s;
        if (c8 < 32) {
            const float* p = x2 + (size_t)row * 256 + c8 * 8;
            s = cvt8(*(const float4*)p, *(const float4*)(p + 4));
        } else if (c8 < 34) {
            const float* p = ax2 + (size_t)row * 16 + (c8 - 32) * 8;
            s = cvt8(*(const float4*)p, *(const float4*)(p + 4));
        } else {
            s = zero8;
        }
        *(short8*)&A2[(size_t)row * 288 + c8 * 8] = s;
    } else if (bx < 356) {                          // ax1p = [ax1 | 0]
        const int row = (bx - 352) * 256 + tid;
        const float* p = ax1 + (size_t)row * 16;
        float4 a = *(const float4*)p,       b = *(const float4*)(p + 4);
        float4 c = *(const float4*)(p + 8), d = *(const float4*)(p + 12);
        short* o = ax1p + (size_t)row * 32;
        *(short8*)o        = cvt8(a, b);
        *(short8*)(o + 8)  = cvt8(c, d);
        *(short8*)(o + 16) = zero8;
        *(short8*)(o + 24) = zero8;
    } else if (bx < 548) {                          // masks: 3072 rows, 16/block
        const int r0 = (bx - 356) * 16;
        const int wave = tid >> 6, lane = tid & 63;
        for (int rr = 0; rr < 16; ++rr) {
            const int row = r0 + rr;
            const int mk = masks[(size_t)row * 256 + tid];
            unsigned long long bal = __ballot(mk != 0);
            if (lane == 0) {
                mb[row * 8 + wave * 2 + 0] = (unsigned int)bal;
                mb[row * 8 + wave * 2 + 1] = (unsigned int)(bal >> 32);
            }
        }
    } else if (bx < 644) {                          // WqT
        const int idx = bx - 548, i = idx >> 5, k8 = idx & 31;
        const int n = tid;
        const float* W = Wq + (size_t)i * 256 * 256;
        short8 s;
#pragma unroll
        for (int j = 0; j < 8; ++j) s[j] = (short)f2bf(W[(size_t)(k8 * 8 + j) * 256 + n]);
        *(short8*)&WqT[(size_t)i * 256 * 256 + (size_t)n * 256 + k8 * 8] = s;
    } else if (bx < 860) {                          // WkT / WvT (K'=288 remap)
        const int idx0 = bx - 644;
        const int kv = idx0 / 108, idx = idx0 % 108;
        const int i = idx / 36, k8 = idx % 36;
        const int n = tid;
        const float* W = (kv ? Wv : Wk) + (size_t)i * 288 * 256;
        short* O = (kv ? WvT : WkT) + (size_t)i * 256 * 288;
        short8 s;
#pragma unroll
        for (int j = 0; j < 8; ++j) {
            const int kp = k8 * 8 + j;
            const int src = (kp < 256) ? kp : (kp < 272 ? kp + 16 : -1);
            s[j] = (src >= 0) ? (short)f2bf(W[(size_t)src * 256 + n]) : (short)0;
        }
        *(short8*)&O[(size_t)n * 288 + k8 * 8] = s;
    } else {                                        // WpT
        const int idx = bx - 860, i = idx >> 5, k8 = idx & 31;
        const int n = tid;
        const float* W = Wp + (size_t)i * 256 * 256;
        short8 s;
#pragma unroll
        for (int j = 0; j < 8; ++j) s[j] = (short)f2bf(W[(size_t)(k8 * 8 + j) * 256 + n]);
        *(short8*)&WpT[(size_t)i * 256 * 256 + (size_t)n * 256 + k8 * 8] = s;
    }
}

// ---------------------------------------------------------------------------
// fused_gemm: frags direct from global bf16, no LDS.
//  0..47    q  = (x1b @ WqT + bq) * QSC  -> qb  (pre-scaled for attention)
//  48..143  kb = A2 @ WkT + bk           -> kbb
//  144..239 vb = A2 @ WvT + bv           -> vbT [i][256][2048] (transposed)
//  240      WeffT = (sum_i Wv_a1_i @ Wp_i)^T  (16x256 -> [n][32], K-padded)
// ---------------------------------------------------------------------------
__global__ __launch_bounds__(256) void fused_gemm(
    const short* __restrict__ x1b, const short* __restrict__ A2,
    const short* __restrict__ WqT, const short* __restrict__ WkT,
    const short* __restrict__ WvT, const float* __restrict__ Wv,
    const short* __restrict__ WpT,
    const float* __restrict__ bq, const float* __restrict__ bk,
    const float* __restrict__ bv,
    short* __restrict__ qb, short* __restrict__ kbb,
    short* __restrict__ vbT, short* __restrict__ WeffT)
{
    const int bx = blockIdx.x;
    const int tid = threadIdx.x;
    const int wave = tid >> 6, lane = tid & 63;
    const int qd = lane >> 4, ml = lane & 15;

    if (bx == 240) {
        // Weff = sum_i Wv_a1_i(16x256) @ Wp_i(256x256); wave handles 4 n-tiles.
        f32x4 wacc[4];
#pragma unroll
        for (int nt = 0; nt < 4; ++nt) wacc[nt] = {0.f, 0.f, 0.f, 0.f};
        for (int i = 0; i < 3; ++i) {
            const float* Wvp = Wv + (size_t)i * 288 * 256;
            const short* Wpt = WpT + (size_t)i * 256 * 256;
            for (int step = 0; step < 8; ++step) {
                const float* ap = Wvp + (size_t)(256 + ml) * 256 + step * 32 + qd * 8;
                short8 af = cvt8(*(const float4*)ap, *(const float4*)(ap + 4));
#pragma unroll
                for (int nt = 0; nt < 4; ++nt) {
                    const int n = (wave * 4 + nt) * 16 + ml;
                    short8 bf = *(const short8*)&Wpt[(size_t)n * 256 + step * 32 + qd * 8];
                    wacc[nt] = __builtin_amdgcn_mfma_f32_16x16x32_bf16(af, bf, wacc[nt], 0, 0, 0);
                }
            }
        }
#pragma unroll
        for (int nt = 0; nt < 4; ++nt) {
            const int n = (wave * 4 + nt) * 16 + ml;
#pragma unroll
            for (int r = 0; r < 4; ++r) {
                WeffT[n * 32 + qd * 4 + r] = (short)f2bf(wacc[nt][r]);
                WeffT[n * 32 + 16 + qd * 4 + r] = 0;   // K-pad (ax1p rows 16..31 are 0)
            }
        }
        return;
    }

    const short *Ab, *Wb;
    const float* bias;
    short* outb;
    int LDA, LDW, nsteps, mode, m0, n0;   // mode: 0 bf16, 1 bf16-transposed, 3 q-scaled
    if (bx < 48) {
        const int i = bx >> 4, t = bx & 15;
        m0 = (t >> 1) * 128; n0 = (t & 1) * 128;
        Ab = x1b; LDA = 256; Wb = WqT + (size_t)i * 256 * 256; LDW = 256;
        nsteps = 8; bias = bq + i * 256; outb = qb + (size_t)i * 1024 * 256; mode = 3;
    } else if (bx < 144) {
        const int idx = bx - 48, i = idx >> 5, t = idx & 31;
        m0 = (t >> 1) * 128; n0 = (t & 1) * 128;
        Ab = A2; LDA = 288; Wb = WkT + (size_t)i * 256 * 288; LDW = 288;
        nsteps = 9; bias = bk + i * 256; outb = kbb + (size_t)i * 2048 * 256; mode = 0;
    } else {
        const int idx = bx - 144, i = idx >> 5, t = idx & 31;
        m0 = (t >> 1) * 128; n0 = (t & 1) * 128;
        Ab = A2; LDA = 288; Wb = WvT + (size_t)i * 256 * 288; LDW = 288;
        nsteps = 9; bias = bv + i * 256; outb = vbT + (size_t)i * 256 * 2048; mode = 1;
    }

    const int wy = wave >> 1, wx = wave & 1;

    f32x4 acc[4][4];
#pragma unroll
    for (int a = 0; a < 4; ++a)
#pragma unroll
        for (int b = 0; b < 4; ++b) acc[a][b] = {0.f, 0.f, 0.f, 0.f};

    for (int step = 0; step < nsteps; ++step) {
        short8 af[4], bf[4];
#pragma unroll
        for (int mt = 0; mt < 4; ++mt)
            af[mt] = *(const short8*)&Ab[(size_t)(m0 + wy * 64 + mt * 16 + ml) * LDA + step * 32 + qd * 8];
#pragma unroll
        for (int nt = 0; nt < 4; ++nt)
            bf[nt] = *(const short8*)&Wb[(size_t)(n0 + wx * 64 + nt * 16 + ml) * LDW + step * 32 + qd * 8];
#pragma unroll
        for (int mt = 0; mt < 4; ++mt)
#pragma unroll
            for (int nt = 0; nt < 4; ++nt)
                acc[mt][nt] = __builtin_amdgcn_mfma_f32_16x16x32_bf16(
                    af[mt], bf[nt], acc[mt][nt], 0, 0, 0);
    }

#pragma unroll
    for (int nt = 0; nt < 4; ++nt) {
        const int col = n0 + wx * 64 + nt * 16 + ml;
        const float bsv = bias[col];
#pragma unroll
        for (int mt = 0; mt < 4; ++mt) {
            const int row0 = m0 + wy * 64 + mt * 16 + qd * 4;
            if (mode == 0) {
#pragma unroll
                for (int r = 0; r < 4; ++r)
                    outb[(size_t)(row0 + r) * 256 + col] = (short)f2bf(acc[mt][nt][r] + bsv);
            } else if (mode == 3) {
#pragma unroll
                for (int r = 0; r < 4; ++r)
                    outb[(size_t)(row0 + r) * 256 + col] = (short)f2bf((acc[mt][nt][r] + bsv) * QSC);
            } else {
                short4v s;
                s.x = (short)f2bf(acc[mt][nt][0] + bsv);
                s.y = (short)f2bf(acc[mt][nt][1] + bsv);
                s.z = (short)f2bf(acc[mt][nt][2] + bsv);
                s.w = (short)f2bf(acc[mt][nt][3] + bsv);
                *(short4v*)&outb[(size_t)col * 2048 + row0] = s;
            }
        }
    }
}

// ---------------------------------------------------------------------------
// attn: zero barriers, direct global frags, bit-masks. q pre-scaled.
// Writes O only (vaux folded into proj via Weff).
// ---------------------------------------------------------------------------
__global__ __launch_bounds__(256) void attn_mfma(
    const short* __restrict__ qb, const short* __restrict__ kbb,
    const short* __restrict__ vbT, const unsigned int* __restrict__ mb,
    short* __restrict__ yb)
{
    const int bx = blockIdx.x;
    const int tc = bx & 1, h = (bx >> 1) & 7, b = (bx >> 4) & 7, i = bx >> 7;
    const size_t bb = (size_t)i * 8 + b;

    __shared__ short Ps[4][32 * 16 * 8];

    const int tid = threadIdx.x;
    const int wave = tid >> 6, lane = tid & 63;
    const int ml = lane & 15, qd = lane >> 4;

    const int t = tc * 64 + wave * 16 + ml;
    short8 af = *(const short8*)&qb[(bb * 128 + t) * 256 + h * HD + qd * 8];

    f32x4 sacc[16];
#pragma unroll
    for (int nt = 0; nt < 16; ++nt) sacc[nt] = {0.f, 0.f, 0.f, 0.f};
#pragma unroll
    for (int nt = 0; nt < 16; ++nt) {
        short8 bf = *(const short8*)&kbb[(bb * 256 + nt * 16 + ml) * 256 + h * HD + qd * 8];
        sacc[nt] = __builtin_amdgcn_mfma_f32_16x16x32_bf16(af, bf, sacc[nt], 0, 0, 0);
    }

    const int tb = tc * 64 + wave * 16 + qd * 4;
    uint4 wlo[4], whi[4];
#pragma unroll
    for (int r = 0; r < 4; ++r) {
        const unsigned int* p = mb + (bb * 128 + tb + r) * 8;
        wlo[r] = *(const uint4*)p;
        whi[r] = *(const uint4*)(p + 4);
    }

    f32x4 rs = {0.f, 0.f, 0.f, 0.f};
#pragma unroll
    for (int nt = 0; nt < 16; ++nt) {
#pragma unroll
        for (int r = 0; r < 4; ++r) {
            unsigned int w;
            switch (nt >> 1) {
                case 0: w = wlo[r].x; break; case 1: w = wlo[r].y; break;
                case 2: w = wlo[r].z; break; case 3: w = wlo[r].w; break;
                case 4: w = whi[r].x; break; case 5: w = whi[r].y; break;
                case 6: w = whi[r].z; break; default: w = whi[r].w; break;
            }
            const bool mk = (w >> ((nt & 1) * 16 + ml)) & 1u;
            float e = mk ? __builtin_amdgcn_exp2f(sacc[nt][r]) : 0.f;
            sacc[nt][r] = e;
            rs[r] += e;
        }
    }
#pragma unroll
    for (int off = 1; off <= 8; off <<= 1) {
#pragma unroll
        for (int r = 0; r < 4; ++r) rs[r] += __shfl_xor(rs[r], off);
    }
    f32x4 pinv, pfill;
#pragma unroll
    for (int r = 0; r < 4; ++r) {
        const bool z = (rs[r] == 0.f);
        pinv[r]  = z ? 0.f : 1.f / rs[r];
        pfill[r] = z ? (1.f / 256.f) : 0.f;
    }

    short* Pw = &Ps[wave][0];
#pragma unroll
    for (int nt = 0; nt < 16; ++nt) {
        const int sgrp = 2 * nt + (ml >> 3);
        const int pos = ml & 7;
#pragma unroll
        for (int r = 0; r < 4; ++r) {
            const float p = sacc[nt][r] * pinv[r] + pfill[r];
            Pw[(sgrp * 16 + qd * 4 + r) * 8 + pos] = (short)f2bf(p);
        }
    }

    f32x4 oacc[2];
    oacc[0] = {0.f, 0.f, 0.f, 0.f};
    oacc[1] = {0.f, 0.f, 0.f, 0.f};
    const short* Vb = vbT + (size_t)i * 256 * 2048 + (size_t)b * 256;
#pragma unroll
    for (int ks = 0; ks < 8; ++ks) {
        short8 pa = *(const short8*)&Pw[((ks * 4 + qd) * 16 + ml) * 8];
#pragma unroll
        for (int n2 = 0; n2 < 2; ++n2) {
            short8 vf = *(const short8*)&Vb[(size_t)(h * HD + n2 * 16 + ml) * 2048 + ks * 32 + qd * 8];
            oacc[n2] = __builtin_amdgcn_mfma_f32_16x16x32_bf16(pa, vf, oacc[n2], 0, 0, 0);
        }
    }

#pragma unroll
    for (int n2 = 0; n2 < 2; ++n2) {
        const int d = h * HD + n2 * 16 + ml;
#pragma unroll
        for (int r = 0; r < 4; ++r) {
            const size_t idx = (bb * 128 + tb + r) * 256 + d;
            yb[idx] = (short)f2bf(oacc[n2][r]);
        }
    }
}

// ---------------------------------------------------------------------------
// proj2: out = sum_i O_i @ Wp_i + ax1 @ Weff + sum_i bp_i.  fp32 out.
// ---------------------------------------------------------------------------
__global__ __launch_bounds__(256) void proj2(
    const short* __restrict__ yb, const short* __restrict__ WpT,
    const short* __restrict__ ax1p, const short* __restrict__ WeffT,
    const float* __restrict__ bp, float* __restrict__ out)
{
    const int bx = blockIdx.x;
    const int m0 = (bx >> 2) * 64, n0 = (bx & 3) * 64;
    const int tid = threadIdx.x;
    const int wave = tid >> 6, lane = tid & 63;
    const int wy = wave >> 1, wx = wave & 1;
    const int qd = lane >> 4, ml = lane & 15;

    f32x4 acc[2][2];
#pragma unroll
    for (int a = 0; a < 2; ++a)
#pragma unroll
        for (int b = 0; b < 2; ++b) acc[a][b] = {0.f, 0.f, 0.f, 0.f};

    for (int i = 0; i < 3; ++i) {
        const short* A = yb + (size_t)i * 1024 * 256;
        const short* W = WpT + (size_t)i * 256 * 256;
#pragma unroll
        for (int step = 0; step < 8; ++step) {
            short8 af[2], bf[2];
#pragma unroll
            for (int mt = 0; mt < 2; ++mt)
                af[mt] = *(const short8*)&A[(size_t)(m0 + wy * 32 + mt * 16 + ml) * 256 + step * 32 + qd * 8];
#pragma unroll
            for (int nt = 0; nt < 2; ++nt)
                bf[nt] = *(const short8*)&W[(size_t)(n0 + wx * 32 + nt * 16 + ml) * 256 + step * 32 + qd * 8];
#pragma unroll
            for (int mt = 0; mt < 2; ++mt)
#pragma unroll
                for (int nt = 0; nt < 2; ++nt)
                    acc[mt][nt] = __builtin_amdgcn_mfma_f32_16x16x32_bf16(
                        af[mt], bf[nt], acc[mt][nt], 0, 0, 0);
        }
    }
    {   // vaux contribution: ax1p(1024x32) @ WeffT(256x32), single K-step
        short8 af[2], bf[2];
#pragma unroll
        for (int mt = 0; mt < 2; ++mt)
            af[mt] = *(const short8*)&ax1p[(size_t)(m0 + wy * 32 + mt * 16 + ml) * 32 + qd * 8];
#pragma unroll
        for (int nt = 0; nt < 2; ++nt)
            bf[nt] = *(const short8*)&WeffT[(size_t)(n0 + wx * 32 + nt * 16 + ml) * 32 + qd * 8];
#pragma unroll
        for (int mt = 0; mt < 2; ++mt)
#pragma unroll
            for (int nt = 0; nt < 2; ++nt)
                acc[mt][nt] = __builtin_amdgcn_mfma_f32_16x16x32_bf16(
                    af[mt], bf[nt], acc[mt][nt], 0, 0, 0);
    }
#pragma unroll
    for (int nt = 0; nt < 2; ++nt) {
        const int col = n0 + wx * 32 + nt * 16 + ml;
        const float b3 = bp[col] + bp[256 + col] + bp[512 + col];
#pragma unroll
        for (int mt = 0; mt < 2; ++mt) {
            const int row0 = m0 + wy * 32 + mt * 16 + qd * 4;
#pragma unroll
            for (int r = 0; r < 4; ++r)
                out[(size_t)(row0 + r) * 256 + col] = acc[mt][nt][r] + b3;
        }
    }
}

extern "C" void kernel_launch(void* const* d_in, const int* in_sizes, int n_in,
                              void* d_out, int out_size, void* d_ws, size_t ws_size,
                              hipStream_t stream)
{
    const float* x1  = (const float*)d_in[0];
    const float* x2  = (const float*)d_in[1];
    const float* ax1 = (const float*)d_in[2];
    const float* ax2 = (const float*)d_in[3];
    const int*   mk  = (const int*)d_in[4];
    const float* Wq  = (const float*)d_in[5];
    const float* bq  = (const float*)d_in[6];
    const float* Wk  = (const float*)d_in[7];
    const float* bk  = (const float*)d_in[8];
    const float* Wv  = (const float*)d_in[9];
    const float* bv  = (const float*)d_in[10];
    const float* Wp  = (const float*)d_in[11];
    const float* bp  = (const float*)d_in[12];

    char* w = (char*)d_ws;
    short* x1b   = (short*)(w + 0);              // 512 KB
    short* A2    = (short*)(w + 524288);         // 1.125 MB
    short* ax1p  = (short*)(w + 1703936);        // 64 KB
    short* WqT   = (short*)(w + 1769472);        // 384 KB
    short* WkT   = (short*)(w + 2162688);        // 432 KB
    short* WvT   = (short*)(w + 2605056);        // 432 KB
    short* WpT   = (short*)(w + 3047424);        // 384 KB
    unsigned int* mbits = (unsigned int*)(w + 3440640);   // 96 KB
    short* WeffT = (short*)(w + 3538944);        // 16 KB
    short* qb    = (short*)(w + 3555328);        // 1.5 MB
    short* kbb   = (short*)(w + 5128192);        // 3 MB
    short* vbT   = (short*)(w + 8273920);        // 3 MB
    short* yb    = (short*)(w + 11419648);       // 1.5 MB

    prep<<<dim3(956), 256, 0, stream>>>(x1, x2, ax1, ax2, mk, Wq, Wk, Wv, Wp,
                                        x1b, A2, ax1p, mbits, WqT, WkT, WvT, WpT);
    fused_gemm<<<dim3(241), 256, 0, stream>>>(x1b, A2, WqT, WkT, WvT, Wv, WpT,
                                              bq, bk, bv, qb, kbb, vbT, WeffT);
    attn_mfma<<<dim3(384), 256, 0, stream>>>(qb, kbb, vbT, mbits, yb);
    proj2<<<dim3(64), 256, 0, stream>>>(yb, WpT, ax1p, WeffT, bp, (float*)d_out);
}

// Round 8
// 129.974 us; speedup vs baseline: 1.0255x; 1.0255x over previous
//
#include <hip/hip_runtime.h>
#include <hip/hip_bf16.h>

// B=8, T1=128, T2=256, C=256, H=8, hd=32, E=32, A1=16, NTYPE=3. fp32 in HBM.
// Round 8: occupancy split — fused_gemm 241->481 blocks (64x128 tiles),
// proj2 64->256 blocks (16x64 tiles). Same math, same K-order per output
// element (bit-identical). prep/attn unchanged from r7.
#define NC 256
#define HD 32

typedef __attribute__((ext_vector_type(8))) short short8;
typedef __attribute__((ext_vector_type(4))) short short4v;
typedef __attribute__((ext_vector_type(4))) float f32x4;

#define QSC (0.17677669529663687f * 1.4426950408889634f)  // 1/sqrt(32)*log2(e)

__device__ __forceinline__ unsigned short f2bf(float f) {
    union { float f; unsigned u; } v; v.f = f;
    unsigned r = v.u + 0x7fffu + ((v.u >> 16) & 1u);   // RNE
    return (unsigned short)(r >> 16);
}
__device__ __forceinline__ short8 cvt8(float4 a, float4 b) {
    short8 s;
    s[0] = (short)f2bf(a.x); s[1] = (short)f2bf(a.y);
    s[2] = (short)f2bf(a.z); s[3] = (short)f2bf(a.w);
    s[4] = (short)f2bf(b.x); s[5] = (short)f2bf(b.y);
    s[6] = (short)f2bf(b.z); s[7] = (short)f2bf(b.w);
    return s;
}

// ---------------------------------------------------------------------------
// prep (UNCHANGED from r7): activations + masks + weight transposes.
//  0..63    x1b        64..351 A2=[x2|ax2|0]   352..355 ax1p
//  356..547 mask bits  548..643 WqT   644..859 WkT/WvT   860..955 WpT
// ---------------------------------------------------------------------------
__global__ __launch_bounds__(256) void prep(
    const float* __restrict__ x1, const float* __restrict__ x2,
    const float* __restrict__ ax1, const float* __restrict__ ax2,
    const int* __restrict__ masks,
    const float* __restrict__ Wq, const float* __restrict__ Wk,
    const float* __restrict__ Wv, const float* __restrict__ Wp,
    short* __restrict__ x1b, short* __restrict__ A2, short* __restrict__ ax1p,
    unsigned int* __restrict__ mb,
    short* __restrict__ WqT, short* __restrict__ WkT, short* __restrict__ WvT,
    short* __restrict__ WpT)
{
    const int bx = blockIdx.x, tid = threadIdx.x;
    const short8 zero8 = {0, 0, 0, 0, 0, 0, 0, 0};

    if (bx < 64) {
        const size_t base = ((size_t)bx * 256 + tid) * 16;
        const float* p = x1 + base;
        float4 a = *(const float4*)p,       b = *(const float4*)(p + 4);
        float4 c = *(const float4*)(p + 8), d = *(const float4*)(p + 12);
        *(short8*)&x1b[base]     = cvt8(a, b);
        *(short8*)&x1b[base + 8] = cvt8(c, d);
    } else if (bx < 352) {
        const int g = (bx - 64) * 256 + tid;
        const int row = g / 36, c8 = g - row * 36;
        short8 s;
        if (c8 < 32) {
            const float* p = x2 + (size_t)row * 256 + c8 * 8;
            s = cvt8(*(const float4*)p, *(const float4*)(p + 4));
        } else if (c8 < 34) {
            const float* p = ax2 + (size_t)row * 16 + (c8 - 32) * 8;
            s = cvt8(*(const float4*)p, *(const float4*)(p + 4));
        } else {
            s = zero8;
        }
        *(short8*)&A2[(size_t)row * 288 + c8 * 8] = s;
    } else if (bx < 356) {
        const int row = (bx - 352) * 256 + tid;
        const float* p = ax1 + (size_t)row * 16;
        float4 a = *(const float4*)p,       b = *(const float4*)(p + 4);
        float4 c = *(const float4*)(p + 8), d = *(const float4*)(p + 12);
        short* o = ax1p + (size_t)row * 32;
        *(short8*)o        = cvt8(a, b);
        *(short8*)(o + 8)  = cvt8(c, d);
        *(short8*)(o + 16) = zero8;
        *(short8*)(o + 24) = zero8;
    } else if (bx < 548) {
        const int r0 = (bx - 356) * 16;
        const int wave = tid >> 6, lane = tid & 63;
        for (int rr = 0; rr < 16; ++rr) {
            const int row = r0 + rr;
            const int mk = masks[(size_t)row * 256 + tid];
            unsigned long long bal = __ballot(mk != 0);
            if (lane == 0) {
                mb[row * 8 + wave * 2 + 0] = (unsigned int)bal;
                mb[row * 8 + wave * 2 + 1] = (unsigned int)(bal >> 32);
            }
        }
    } else if (bx < 644) {
        const int idx = bx - 548, i = idx >> 5, k8 = idx & 31;
        const int n = tid;
        const float* W = Wq + (size_t)i * 256 * 256;
        short8 s;
#pragma unroll
        for (int j = 0; j < 8; ++j) s[j] = (short)f2bf(W[(size_t)(k8 * 8 + j) * 256 + n]);
        *(short8*)&WqT[(size_t)i * 256 * 256 + (size_t)n * 256 + k8 * 8] = s;
    } else if (bx < 860) {
        const int idx0 = bx - 644;
        const int kv = idx0 / 108, idx = idx0 % 108;
        const int i = idx / 36, k8 = idx % 36;
        const int n = tid;
        const float* W = (kv ? Wv : Wk) + (size_t)i * 288 * 256;
        short* O = (kv ? WvT : WkT) + (size_t)i * 256 * 288;
        short8 s;
#pragma unroll
        for (int j = 0; j < 8; ++j) {
            const int kp = k8 * 8 + j;
            const int src = (kp < 256) ? kp : (kp < 272 ? kp + 16 : -1);
            s[j] = (src >= 0) ? (short)f2bf(W[(size_t)src * 256 + n]) : (short)0;
        }
        *(short8*)&O[(size_t)n * 288 + k8 * 8] = s;
    } else {
        const int idx = bx - 860, i = idx >> 5, k8 = idx & 31;
        const int n = tid;
        const float* W = Wp + (size_t)i * 256 * 256;
        short8 s;
#pragma unroll
        for (int j = 0; j < 8; ++j) s[j] = (short)f2bf(W[(size_t)(k8 * 8 + j) * 256 + n]);
        *(short8*)&WpT[(size_t)i * 256 * 256 + (size_t)n * 256 + k8 * 8] = s;
    }
}

// ---------------------------------------------------------------------------
// fused_gemm: 64x128 block tiles, wave = 32x64 (acc[2][4]) -> 481 blocks
// (~1.9 blocks/CU = 2 waves/SIMD for latency hiding).
//  0..95    q  = (x1b @ WqT + bq) * QSC -> qb
//  96..287  kb = A2 @ WkT + bk          -> kbb
//  288..479 vb = A2 @ WvT + bv          -> vbT (transposed store)
//  480      WeffT = (sum_i Wv_a1_i @ Wp_i)^T
// ---------------------------------------------------------------------------
__global__ __launch_bounds__(256) void fused_gemm(
    const short* __restrict__ x1b, const short* __restrict__ A2,
    const short* __restrict__ WqT, const short* __restrict__ WkT,
    const short* __restrict__ WvT, const float* __restrict__ Wv,
    const short* __restrict__ WpT,
    const float* __restrict__ bq, const float* __restrict__ bk,
    const float* __restrict__ bv,
    short* __restrict__ qb, short* __restrict__ kbb,
    short* __restrict__ vbT, short* __restrict__ WeffT)
{
    const int bx = blockIdx.x;
    const int tid = threadIdx.x;
    const int wave = tid >> 6, lane = tid & 63;
    const int qd = lane >> 4, ml = lane & 15;

    if (bx == 480) {
        f32x4 wacc[4];
#pragma unroll
        for (int nt = 0; nt < 4; ++nt) wacc[nt] = {0.f, 0.f, 0.f, 0.f};
        for (int i = 0; i < 3; ++i) {
            const float* Wvp = Wv + (size_t)i * 288 * 256;
            const short* Wpt = WpT + (size_t)i * 256 * 256;
            for (int step = 0; step < 8; ++step) {
                const float* ap = Wvp + (size_t)(256 + ml) * 256 + step * 32 + qd * 8;
                short8 af = cvt8(*(const float4*)ap, *(const float4*)(ap + 4));
#pragma unroll
                for (int nt = 0; nt < 4; ++nt) {
                    const int n = (wave * 4 + nt) * 16 + ml;
                    short8 bf = *(const short8*)&Wpt[(size_t)n * 256 + step * 32 + qd * 8];
                    wacc[nt] = __builtin_amdgcn_mfma_f32_16x16x32_bf16(af, bf, wacc[nt], 0, 0, 0);
                }
            }
        }
#pragma unroll
        for (int nt = 0; nt < 4; ++nt) {
            const int n = (wave * 4 + nt) * 16 + ml;
#pragma unroll
            for (int r = 0; r < 4; ++r) {
                WeffT[n * 32 + qd * 4 + r] = (short)f2bf(wacc[nt][r]);
                WeffT[n * 32 + 16 + qd * 4 + r] = 0;
            }
        }
        return;
    }

    const short *Ab, *Wb;
    const float* bias;
    short* outb;
    int LDA, LDW, nsteps, mode, m0, n0;   // mode: 0 bf16, 1 transposed, 3 q-scaled
    if (bx < 96) {
        const int i = bx >> 5, t = bx & 31;
        m0 = (t >> 1) * 64; n0 = (t & 1) * 128;
        Ab = x1b; LDA = 256; Wb = WqT + (size_t)i * 256 * 256; LDW = 256;
        nsteps = 8; bias = bq + i * 256; outb = qb + (size_t)i * 1024 * 256; mode = 3;
    } else if (bx < 288) {
        const int idx = bx - 96, i = idx >> 6, t = idx & 63;
        m0 = (t >> 1) * 64; n0 = (t & 1) * 128;
        Ab = A2; LDA = 288; Wb = WkT + (size_t)i * 256 * 288; LDW = 288;
        nsteps = 9; bias = bk + i * 256; outb = kbb + (size_t)i * 2048 * 256; mode = 0;
    } else {
        const int idx = bx - 288, i = idx >> 6, t = idx & 63;
        m0 = (t >> 1) * 64; n0 = (t & 1) * 128;
        Ab = A2; LDA = 288; Wb = WvT + (size_t)i * 256 * 288; LDW = 288;
        nsteps = 9; bias = bv + i * 256; outb = vbT + (size_t)i * 256 * 2048; mode = 1;
    }

    const int wy = wave >> 1, wx = wave & 1;

    f32x4 acc[2][4];
#pragma unroll
    for (int a = 0; a < 2; ++a)
#pragma unroll
        for (int b = 0; b < 4; ++b) acc[a][b] = {0.f, 0.f, 0.f, 0.f};

    for (int step = 0; step < nsteps; ++step) {
        short8 af[2], bf[4];
#pragma unroll
        for (int mt = 0; mt < 2; ++mt)
            af[mt] = *(const short8*)&Ab[(size_t)(m0 + wy * 32 + mt * 16 + ml) * LDA + step * 32 + qd * 8];
#pragma unroll
        for (int nt = 0; nt < 4; ++nt)
            bf[nt] = *(const short8*)&Wb[(size_t)(n0 + wx * 64 + nt * 16 + ml) * LDW + step * 32 + qd * 8];
#pragma unroll
        for (int mt = 0; mt < 2; ++mt)
#pragma unroll
            for (int nt = 0; nt < 4; ++nt)
                acc[mt][nt] = __builtin_amdgcn_mfma_f32_16x16x32_bf16(
                    af[mt], bf[nt], acc[mt][nt], 0, 0, 0);
    }

#pragma unroll
    for (int nt = 0; nt < 4; ++nt) {
        const int col = n0 + wx * 64 + nt * 16 + ml;
        const float bsv = bias[col];
#pragma unroll
        for (int mt = 0; mt < 2; ++mt) {
            const int row0 = m0 + wy * 32 + mt * 16 + qd * 4;
            if (mode == 0) {
#pragma unroll
                for (int r = 0; r < 4; ++r)
                    outb[(size_t)(row0 + r) * 256 + col] = (short)f2bf(acc[mt][nt][r] + bsv);
            } else if (mode == 3) {
#pragma unroll
                for (int r = 0; r < 4; ++r)
                    outb[(size_t)(row0 + r) * 256 + col] = (short)f2bf((acc[mt][nt][r] + bsv) * QSC);
            } else {
                short4v s;
                s.x = (short)f2bf(acc[mt][nt][0] + bsv);
                s.y = (short)f2bf(acc[mt][nt][1] + bsv);
                s.z = (short)f2bf(acc[mt][nt][2] + bsv);
                s.w = (short)f2bf(acc[mt][nt][3] + bsv);
                *(short4v*)&outb[(size_t)col * 2048 + row0] = s;
            }
        }
    }
}

// ---------------------------------------------------------------------------
// attn (UNCHANGED from r7): zero barriers, direct global frags, bit-masks.
// ---------------------------------------------------------------------------
__global__ __launch_bounds__(256) void attn_mfma(
    const short* __restrict__ qb, const short* __restrict__ kbb,
    const short* __restrict__ vbT, const unsigned int* __restrict__ mb,
    short* __restrict__ yb)
{
    const int bx = blockIdx.x;
    const int tc = bx & 1, h = (bx >> 1) & 7, b = (bx >> 4) & 7, i = bx >> 7;
    const size_t bb = (size_t)i * 8 + b;

    __shared__ short Ps[4][32 * 16 * 8];

    const int tid = threadIdx.x;
    const int wave = tid >> 6, lane = tid & 63;
    const int ml = lane & 15, qd = lane >> 4;

    const int t = tc * 64 + wave * 16 + ml;
    short8 af = *(const short8*)&qb[(bb * 128 + t) * 256 + h * HD + qd * 8];

    f32x4 sacc[16];
#pragma unroll
    for (int nt = 0; nt < 16; ++nt) sacc[nt] = {0.f, 0.f, 0.f, 0.f};
#pragma unroll
    for (int nt = 0; nt < 16; ++nt) {
        short8 bf = *(const short8*)&kbb[(bb * 256 + nt * 16 + ml) * 256 + h * HD + qd * 8];
        sacc[nt] = __builtin_amdgcn_mfma_f32_16x16x32_bf16(af, bf, sacc[nt], 0, 0, 0);
    }

    const int tb = tc * 64 + wave * 16 + qd * 4;
    uint4 wlo[4], whi[4];
#pragma unroll
    for (int r = 0; r < 4; ++r) {
        const unsigned int* p = mb + (bb * 128 + tb + r) * 8;
        wlo[r] = *(const uint4*)p;
        whi[r] = *(const uint4*)(p + 4);
    }

    f32x4 rs = {0.f, 0.f, 0.f, 0.f};
#pragma unroll
    for (int nt = 0; nt < 16; ++nt) {
#pragma unroll
        for (int r = 0; r < 4; ++r) {
            unsigned int w;
            switch (nt >> 1) {
                case 0: w = wlo[r].x; break; case 1: w = wlo[r].y; break;
                case 2: w = wlo[r].z; break; case 3: w = wlo[r].w; break;
                case 4: w = whi[r].x; break; case 5: w = whi[r].y; break;
                case 6: w = whi[r].z; break; default: w = whi[r].w; break;
            }
            const bool mk = (w >> ((nt & 1) * 16 + ml)) & 1u;
            float e = mk ? __builtin_amdgcn_exp2f(sacc[nt][r]) : 0.f;
            sacc[nt][r] = e;
            rs[r] += e;
        }
    }
#pragma unroll
    for (int off = 1; off <= 8; off <<= 1) {
#pragma unroll
        for (int r = 0; r < 4; ++r) rs[r] += __shfl_xor(rs[r], off);
    }
    f32x4 pinv, pfill;
#pragma unroll
    for (int r = 0; r < 4; ++r) {
        const bool z = (rs[r] == 0.f);
        pinv[r]  = z ? 0.f : 1.f / rs[r];
        pfill[r] = z ? (1.f / 256.f) : 0.f;
    }

    short* Pw = &Ps[wave][0];
#pragma unroll
    for (int nt = 0; nt < 16; ++nt) {
        const int sgrp = 2 * nt + (ml >> 3);
        const int pos = ml & 7;
#pragma unroll
        for (int r = 0; r < 4; ++r) {
            const float p = sacc[nt][r] * pinv[r] + pfill[r];
            Pw[(sgrp * 16 + qd * 4 + r) * 8 + pos] = (short)f2bf(p);
        }
    }

    f32x4 oacc[2];
    oacc[0] = {0.f, 0.f, 0.f, 0.f};
    oacc[1] = {0.f, 0.f, 0.f, 0.f};
    const short* Vb = vbT + (size_t)i * 256 * 2048 + (size_t)b * 256;
#pragma unroll
    for (int ks = 0; ks < 8; ++ks) {
        short8 pa = *(const short8*)&Pw[((ks * 4 + qd) * 16 + ml) * 8];
#pragma unroll
        for (int n2 = 0; n2 < 2; ++n2) {
            short8 vf = *(const short8*)&Vb[(size_t)(h * HD + n2 * 16 + ml) * 2048 + ks * 32 + qd * 8];
            oacc[n2] = __builtin_amdgcn_mfma_f32_16x16x32_bf16(pa, vf, oacc[n2], 0, 0, 0);
        }
    }

#pragma unroll
    for (int n2 = 0; n2 < 2; ++n2) {
        const int d = h * HD + n2 * 16 + ml;
#pragma unroll
        for (int r = 0; r < 4; ++r) {
            const size_t idx = (bb * 128 + tb + r) * 256 + d;
            yb[idx] = (short)f2bf(oacc[n2][r]);
        }
    }
}

// ---------------------------------------------------------------------------
// proj2: 16x64 block tiles, wave = one 16x16 acc -> 256 blocks (1/CU).
// out = sum_i O_i @ Wp_i + ax1 @ Weff + sum_i bp_i.
// ---------------------------------------------------------------------------
__global__ __launch_bounds__(256) void proj2(
    const short* __restrict__ yb, const short* __restrict__ WpT,
    const short* __restrict__ ax1p, const short* __restrict__ WeffT,
    const float* __restrict__ bp, float* __restrict__ out)
{
    const int bx = blockIdx.x;
    const int m0 = (bx >> 2) * 16, n0 = (bx & 3) * 64;
    const int tid = threadIdx.x;
    const int wave = tid >> 6, lane = tid & 63;
    const int qd = lane >> 4, ml = lane & 15;
    const int col = n0 + wave * 16 + ml;

    f32x4 acc = {0.f, 0.f, 0.f, 0.f};

    for (int i = 0; i < 3; ++i) {
        const short* A = yb + (size_t)i * 1024 * 256;
        const short* W = WpT + (size_t)i * 256 * 256;
#pragma unroll
        for (int step = 0; step < 8; ++step) {
            short8 af = *(const short8*)&A[(size_t)(m0 + ml) * 256 + step * 32 + qd * 8];
            short8 bf = *(const short8*)&W[(size_t)col * 256 + step * 32 + qd * 8];
            acc = __builtin_amdgcn_mfma_f32_16x16x32_bf16(af, bf, acc, 0, 0, 0);
        }
    }
    {   // vaux term: ax1p(1024x32) @ WeffT, single K-step
        short8 af = *(const short8*)&ax1p[(size_t)(m0 + ml) * 32 + qd * 8];
        short8 bf = *(const short8*)&WeffT[(size_t)col * 32 + qd * 8];
        acc = __builtin_amdgcn_mfma_f32_16x16x32_bf16(af, bf, acc, 0, 0, 0);
    }
    const float b3 = bp[col] + bp[256 + col] + bp[512 + col];
    const int row0 = m0 + qd * 4;
#pragma unroll
    for (int r = 0; r < 4; ++r)
        out[(size_t)(row0 + r) * 256 + col] = acc[r] + b3;
}

extern "C" void kernel_launch(void* const* d_in, const int* in_sizes, int n_in,
                              void* d_out, int out_size, void* d_ws, size_t ws_size,
                              hipStream_t stream)
{
    const float* x1  = (const float*)d_in[0];
    const float* x2  = (const float*)d_in[1];
    const float* ax1 = (const float*)d_in[2];
    const float* ax2 = (const float*)d_in[3];
    const int*   mk  = (const int*)d_in[4];
    const float* Wq  = (const float*)d_in[5];
    const float* bq  = (const float*)d_in[6];
    const float* Wk  = (const float*)d_in[7];
    const float* bk  = (const float*)d_in[8];
    const float* Wv  = (const float*)d_in[9];
    const float* bv  = (const float*)d_in[10];
    const float* Wp  = (const float*)d_in[11];
    const float* bp  = (const float*)d_in[12];

    char* w = (char*)d_ws;
    short* x1b   = (short*)(w + 0);              // 512 KB
    short* A2    = (short*)(w + 524288);         // 1.125 MB
    short* ax1p  = (short*)(w + 1703936);        // 64 KB
    short* WqT   = (short*)(w + 1769472);        // 384 KB
    short* WkT   = (short*)(w + 2162688);        // 432 KB
    short* WvT   = (short*)(w + 2605056);        // 432 KB
    short* WpT   = (short*)(w + 3047424);        // 384 KB
    unsigned int* mbits = (unsigned int*)(w + 3440640);   // 96 KB
    short* WeffT = (short*)(w + 3538944);        // 16 KB
    short* qb    = (short*)(w + 3555328);        // 1.5 MB
    short* kbb   = (short*)(w + 5128192);        // 3 MB
    short* vbT   = (short*)(w + 8273920);        // 3 MB
    short* yb    = (short*)(w + 11419648);       // 1.5 MB

    prep<<<dim3(956), 256, 0, stream>>>(x1, x2, ax1, ax2, mk, Wq, Wk, Wv, Wp,
                                        x1b, A2, ax1p, mbits, WqT, WkT, WvT, WpT);
    fused_gemm<<<dim3(481), 256, 0, stream>>>(x1b, A2, WqT, WkT, WvT, Wv, WpT,
                                              bq, bk, bv, qb, kbb, vbT, WeffT);
    attn_mfma<<<dim3(384), 256, 0, stream>>>(qb, kbb, vbT, mbits, yb);
    proj2<<<dim3(256), 256, 0, stream>>>(yb, WpT, ax1p, WeffT, bp, (float*)d_out);
}